// Round 10
// baseline (178.625 us; speedup 1.0000x reference)
//
#include <hip/hip_runtime.h>
#include <hip/hip_fp16.h>

#define B_    4
#define CIN_  64
#define COUT_ 64
#define N_    16384
#define K_    8
#define CAP_  16     // index-bucket capacity (Poisson(8): P(>16) ~ 0.3%)

#define EDGES_PER_B (K_ * N_)            // 131072
#define TOT_EDGES   (B_ * EDGES_PER_B)   // 524288

// ===========================================================================
// PATH E (~84.3 MiB ws, 3 dispatch nodes):
//   memset(cursor+ws2) -> fc_contribE -> fc_gatherE
// contrib computes the per-edge scalar c = pos_j.ft + h IN the GEMM kernel
// (pos_j is a wave-uniform L2 broadcast load) and stores it DENSELY in
// edge-major order (fp16, coalesced streaming). The gather reads one
// contiguous 128-B row per edge (67 MB logical vs 268 MB in the previous
// source-row design) and just sums.
// ===========================================================================

// --- contrib: GEMM -> per-edge scalars, dense; bucket holds edge ids -------
__global__ __launch_bounds__(512, 4) void fc_contribE(
    const float* __restrict__ feat,     // [B, CIN, N]
    const float* __restrict__ theta,    // [3, CIN, COUT]
    const float* __restrict__ wbias,    // [CIN, COUT]
    const int*   __restrict__ nbh,      // [B, K, N]
    const float* __restrict__ pos,      // [B, 3, N]
    int*         __restrict__ cursor,   // [B, N]   (zeroed)
    int*         __restrict__ bucket,   // [B, N, CAP] edge ids (n*K+k)
    __half*      __restrict__ cval,     // [B, N*K, 64] per-edge scalars
    float*       __restrict__ ws2)      // [B, N, 64] fp32 overflow (zeroed)
{
    __shared__ float4 Wl[CIN_ * COUT_];   // 64 KiB
    __shared__ float  Fl[CIN_ * 64];      // 16 KiB

    const int tid  = threadIdx.x;
    const int lane = tid & 63;            // o
    const int w    = tid >> 6;            // wave 0..7

    const int blocks_per_b = N_ / 128;    // 128
    const int b     = blockIdx.x / blocks_per_b;
    const int nbase = (blockIdx.x % blocks_per_b) * 128;

    for (int e = tid; e < CIN_ * COUT_; e += 512) {
        const int i = e >> 6, o = e & 63;
        float4 wv;
        wv.x = theta[0 * CIN_ * COUT_ + i * COUT_ + o];
        wv.y = theta[1 * CIN_ * COUT_ + i * COUT_ + o];
        wv.z = theta[2 * CIN_ * COUT_ + i * COUT_ + o];
        wv.w = wbias[i * COUT_ + o];
        Wl[e] = wv;
    }

    const float* featb = feat + (size_t)b * CIN_ * N_;
    const float* posb  = pos  + (size_t)b * 3 * N_;
    const int*   nbhb  = nbh  + (size_t)b * K_ * N_;
    int*         curb  = cursor + b * N_;
    int*         bkb   = bucket + (size_t)b * N_ * CAP_;
    __half*      cvb   = cval + ((size_t)b * EDGES_PER_B << 6);
    float*       ws2b  = ws2 + ((size_t)b * N_ << 6);

    for (int t = 0; t < 2; ++t) {
        const int n0 = nbase + t * 64;
        const int nn = w * 8;             // this wave's 8 points

        __syncthreads();   // Wl ready (t=0) / previous Fl readers done
        for (int r = 0; r < 8; ++r) {
            const int i = r * 8 + w;
            Fl[i * 64 + lane] = featb[(size_t)i * N_ + n0 + lane];
        }

        // --- edge prep: lane l claims slot for (point l>>3, edge l&7) ------
        const int pe = lane >> 3;                 // local point 0..7
        const int ke = lane & 7;                  // edge 0..7
        const int ne = n0 + nn + pe;
        const int je = nbhb[ke * N_ + ne];
        const int sle = atomicAdd(&curb[je], 1);
        if (sle < CAP_) bkb[je * CAP_ + sle] = ne * K_ + ke;   // edge id

        __syncthreads();   // Fl ready

        float4 acc[8];
        #pragma unroll
        for (int j = 0; j < 8; ++j) acc[j] = make_float4(0.f, 0.f, 0.f, 0.f);

        #pragma unroll 2
        for (int i = 0; i < CIN_; ++i) {
            const float4 wv = Wl[i * 64 + lane];              // b128, conflict-free
            const float4 fA = *(const float4*)&Fl[i * 64 + nn];     // broadcast
            const float4 fB = *(const float4*)&Fl[i * 64 + nn + 4]; // broadcast
            const float fs[8] = {fA.x, fA.y, fA.z, fA.w, fB.x, fB.y, fB.z, fB.w};
            #pragma unroll
            for (int j = 0; j < 8; ++j) {
                acc[j].x = fmaf(wv.x, fs[j], acc[j].x);
                acc[j].y = fmaf(wv.y, fs[j], acc[j].y);
                acc[j].z = fmaf(wv.z, fs[j], acc[j].z);
                acc[j].w = fmaf(wv.w, fs[j], acc[j].w);
            }
        }

        const unsigned long long ovf = __ballot(sle >= CAP_);   // bit = p*8+k

        #pragma unroll
        for (int p = 0; p < 8; ++p) {
            const int n = n0 + nn + p;
            const float px = posb[0 * N_ + n];
            const float py = posb[1 * N_ + n];
            const float pz = posb[2 * N_ + n];
            float4 a = acc[p];
            a.w = fmaf(-px, a.x, fmaf(-py, a.y, fmaf(-pz, a.z, a.w)));  // h

            __half* crow = cvb + ((size_t)(n * K_) << 6) + lane;
            #pragma unroll
            for (int k = 0; k < K_; ++k) {
                const int jt = nbhb[k * N_ + n];      // wave-uniform bcast
                const float qx = posb[jt];            // L2-resident bcast
                const float qy = posb[N_ + jt];
                const float qz = posb[2 * N_ + jt];
                const float c  = fmaf(qx, a.x, fmaf(qy, a.y, fmaf(qz, a.z, a.w)));
                crow[(size_t)k << 6] = __float2half(c);   // dense 128-B store
                if ((ovf >> (p * 8 + k)) & 1ull)          // rare; no shfl needed
                    atomicAdd(&ws2b[((size_t)jt << 6) + lane], c);
            }
        }
    }
}

// --- gather: per target j, sum cval rows of its bucket edges ---------------
__global__ __launch_bounds__(512, 8) void fc_gatherE(
    const __half* __restrict__ cval,    // [B, N*K, 64]
    const int*    __restrict__ bucket,  // [B, N, CAP]
    const int*    __restrict__ cursor,  // [B, N] total in-degree
    const float*  __restrict__ ws2,     // [B, N, 64] overflow sums
    const float*  __restrict__ bias,
    float*        __restrict__ out)     // [B, COUT, N]
{
    __shared__ float T[64][65];          // 16.25 KiB -> high occupancy
    const int tid  = threadIdx.x;
    const int lane = tid & 63;           // o
    const int w    = tid >> 6;           // 0..7

    const int tiles_per_b = N_ / 64;     // 256
    const int b  = blockIdx.x / tiles_per_b;
    const int n0 = (blockIdx.x % tiles_per_b) * 64;

    const __half* cvb  = cval + ((size_t)b * EDGES_PER_B << 6);
    const int*    bkb  = bucket + (size_t)b * N_ * CAP_;
    const float*  ws2b = ws2 + ((size_t)b * N_ << 6);

    for (int g = 0; g < 8; ++g) {
        const int jj = w * 8 + g;
        const int j  = n0 + jj;
        const int cnt_tot = cursor[b * N_ + j];
        const int cnt = cnt_tot < CAP_ ? cnt_tot : CAP_;

        // parallel index fetch: lane e holds bucket entry e
        const int myidx = (lane < cnt) ? bkb[j * CAP_ + lane] : 0;

        float acc = (cnt_tot > CAP_) ? ws2b[((size_t)j << 6) + lane] : 0.f;

        int e = 0;
        for (; e + 4 <= cnt; e += 4) {          // 4 row loads in flight
            const int m0 = __shfl(myidx, e + 0);
            const int m1 = __shfl(myidx, e + 1);
            const int m2 = __shfl(myidx, e + 2);
            const int m3 = __shfl(myidx, e + 3);
            const float c0 = __half2float(cvb[((size_t)m0 << 6) + lane]);
            const float c1 = __half2float(cvb[((size_t)m1 << 6) + lane]);
            const float c2 = __half2float(cvb[((size_t)m2 << 6) + lane]);
            const float c3 = __half2float(cvb[((size_t)m3 << 6) + lane]);
            acc += (c0 + c1) + (c2 + c3);
        }
        for (; e < cnt; ++e) {
            const int m = __shfl(myidx, e);
            acc += __half2float(cvb[((size_t)m << 6) + lane]);
        }
        T[jj][lane] = acc;
    }
    __syncthreads();

    float* outb = out + (size_t)b * COUT_ * N_;
    for (int r = 0; r < 8; ++r) {
        const int o = r * 8 + w;
        outb[(size_t)o * N_ + n0 + lane] = T[lane][o] + bias[o];  // coalesced
    }
}

// ===========================================================================
// PATH C (16 MiB ws): verified atomic-scatter fallback.
// ===========================================================================
__global__ __launch_bounds__(256) void flexconv_main(
    const float* __restrict__ feat,
    const float* __restrict__ theta,
    const float* __restrict__ wbias,
    const int*   __restrict__ nbh,
    const float* __restrict__ pos,
    float*       __restrict__ ws)
{
    __shared__ float4 Wl[CIN_ * COUT_];
    __shared__ float  Fl[CIN_ * 64];

    const int tid  = threadIdx.x;
    const int lane = tid & 63;
    const int w    = tid >> 6;

    const int blocks_per_b = N_ / 128;
    const int b     = blockIdx.x / blocks_per_b;
    const int nbase = (blockIdx.x % blocks_per_b) * 128;

    for (int e = tid; e < CIN_ * COUT_; e += 256) {
        const int i = e >> 6, o = e & 63;
        float4 wv;
        wv.x = theta[0 * CIN_ * COUT_ + i * COUT_ + o];
        wv.y = theta[1 * CIN_ * COUT_ + i * COUT_ + o];
        wv.z = theta[2 * CIN_ * COUT_ + i * COUT_ + o];
        wv.w = wbias[i * COUT_ + o];
        Wl[e] = wv;
    }

    const float* featb = feat + (size_t)b * CIN_ * N_;
    const float* posb  = pos  + (size_t)b * 3 * N_;
    const int*   nbhb  = nbh  + (size_t)b * K_ * N_;
    float*       wsb   = ws   + (size_t)b * N_ * COUT_;

    for (int t = 0; t < 2; ++t) {
        const int n0 = nbase + t * 64;

        __syncthreads();
        for (int r = 0; r < 16; ++r) {
            const int i = r * 4 + w;
            Fl[i * 64 + lane] = featb[(size_t)i * N_ + n0 + lane];
        }
        __syncthreads();

        for (int g = 0; g < 4; ++g) {
            const int nn = w * 16 + g * 4;
            float4 acc[4];
            #pragma unroll
            for (int j = 0; j < 4; ++j) acc[j] = make_float4(0.f, 0.f, 0.f, 0.f);

            #pragma unroll 8
            for (int i = 0; i < CIN_; ++i) {
                const float4 wv = Wl[i * 64 + lane];
                const float f0 = Fl[i * 64 + nn + 0];
                const float f1 = Fl[i * 64 + nn + 1];
                const float f2 = Fl[i * 64 + nn + 2];
                const float f3 = Fl[i * 64 + nn + 3];
                acc[0].x = fmaf(wv.x, f0, acc[0].x);
                acc[0].y = fmaf(wv.y, f0, acc[0].y);
                acc[0].z = fmaf(wv.z, f0, acc[0].z);
                acc[0].w = fmaf(wv.w, f0, acc[0].w);
                acc[1].x = fmaf(wv.x, f1, acc[1].x);
                acc[1].y = fmaf(wv.y, f1, acc[1].y);
                acc[1].z = fmaf(wv.z, f1, acc[1].z);
                acc[1].w = fmaf(wv.w, f1, acc[1].w);
                acc[2].x = fmaf(wv.x, f2, acc[2].x);
                acc[2].y = fmaf(wv.y, f2, acc[2].y);
                acc[2].z = fmaf(wv.z, f2, acc[2].z);
                acc[2].w = fmaf(wv.w, f2, acc[2].w);
                acc[3].x = fmaf(wv.x, f3, acc[3].x);
                acc[3].y = fmaf(wv.y, f3, acc[3].y);
                acc[3].z = fmaf(wv.z, f3, acc[3].z);
                acc[3].w = fmaf(wv.w, f3, acc[3].w);
            }

            #pragma unroll
            for (int j = 0; j < 4; ++j) {
                const int n = n0 + nn + j;
                const float px = posb[0 * N_ + n];
                const float py = posb[1 * N_ + n];
                const float pz = posb[2 * N_ + n];
                const float4 a = acc[j];
                #pragma unroll
                for (int k = 0; k < K_; ++k) {
                    const int idx = nbhb[k * N_ + n];
                    const float dx = posb[0 * N_ + idx] - px;
                    const float dy = posb[1 * N_ + idx] - py;
                    const float dz = posb[2 * N_ + idx] - pz;
                    const float c  = fmaf(dx, a.x, fmaf(dy, a.y, fmaf(dz, a.z, a.w)));
                    atomicAdd(&wsb[(size_t)idx * COUT_ + lane], c);
                }
            }
        }
    }
}

__global__ __launch_bounds__(256) void flexconv_finish(
    const float* __restrict__ ws,
    const float* __restrict__ bias,
    float*       __restrict__ out)
{
    __shared__ float T[64][65];
    const int tid  = threadIdx.x;
    const int lane = tid & 63;
    const int w    = tid >> 6;

    const int tiles_per_b = N_ / 64;
    const int b  = blockIdx.x / tiles_per_b;
    const int n0 = (blockIdx.x % tiles_per_b) * 64;

    const float* wsb = ws + (size_t)b * N_ * COUT_;
    for (int r = 0; r < 16; ++r) {
        const int nn = r * 4 + w;
        T[nn][lane] = wsb[(size_t)(n0 + nn) * COUT_ + lane];
    }
    __syncthreads();

    float* outb = out + (size_t)b * COUT_ * N_;
    for (int r = 0; r < 16; ++r) {
        const int o = r * 4 + w;
        outb[(size_t)o * N_ + n0 + lane] = T[lane][o] + bias[o];
    }
}

// ===========================================================================
extern "C" void kernel_launch(void* const* d_in, const int* in_sizes, int n_in,
                              void* d_out, int out_size, void* d_ws, size_t ws_size,
                              hipStream_t stream) {
    const float* features = (const float*)d_in[0];
    const float* theta    = (const float*)d_in[1];
    const float* wbias    = (const float*)d_in[2];
    const int*   nbh      = (const int*)  d_in[3];
    const float* pos      = (const float*)d_in[4];
    const float* bias     = (const float*)d_in[5];
    float* out = (float*)d_out;

    // ---- Path E: dense edge-scalar store + index buckets (~84.3 MiB) ----
    {
        const size_t cval_bytes   = ((size_t)TOT_EDGES << 6) * sizeof(__half); // 64 MiB
        const size_t bucket_bytes = (size_t)B_ * N_ * CAP_ * sizeof(int);      // 4 MiB
        const size_t cursor_bytes = (size_t)B_ * N_ * sizeof(int);             // 256 KiB
        const size_t ws2_bytes    = ((size_t)B_ * N_ << 6) * sizeof(float);    // 16 MiB

        size_t off = 0;
        __half* cval   = (__half*)((char*)d_ws + off); off += cval_bytes;
        int*    bucket = (int*)   ((char*)d_ws + off); off += bucket_bytes;
        int*    cursor = (int*)   ((char*)d_ws + off); off += cursor_bytes;
        float*  ws2    = (float*) ((char*)d_ws + off); off += ws2_bytes;

        if (ws_size >= off) {
            // one memset covers cursor + ws2 (contiguous)
            hipMemsetAsync(cursor, 0, cursor_bytes + ws2_bytes, stream);
            fc_contribE<<<B_ * (N_ / 128), 512, 0, stream>>>(features, theta, wbias,
                                                             nbh, pos, cursor,
                                                             bucket, cval, ws2);
            fc_gatherE<<<B_ * (N_ / 64), 512, 0, stream>>>(cval, bucket, cursor,
                                                           ws2, bias, out);
            return;
        }
    }

    // ---- Path C: atomic fallback (16 MiB) ----
    {
        float* ws = (float*)d_ws;
        const size_t ws_bytes = (size_t)B_ * N_ * COUT_ * sizeof(float);
        hipMemsetAsync(ws, 0, ws_bytes, stream);
        flexconv_main<<<B_ * (N_ / 128), 256, 0, stream>>>(features, theta, wbias,
                                                           nbh, pos, ws);
        flexconv_finish<<<B_ * (N_ / 64), 256, 0, stream>>>(ws, bias, out);
    }
}

// Round 11
// 163.500 us; speedup vs baseline: 1.0925x; 1.0925x over previous
//
#include <hip/hip_runtime.h>
#include <hip/hip_fp16.h>

#define B_    4
#define CIN_  64
#define COUT_ 64
#define N_    16384
#define K_    8
#define CAP_  16     // index-bucket capacity (Poisson(8): P(>16) ~ 0.3%)

#define EDGES_PER_B (K_ * N_)            // 131072
#define TOT_EDGES   (B_ * EDGES_PER_B)   // 524288

// ===========================================================================
// PATH D2 (~52.3 MiB ws, 3 dispatch nodes):
//   memset(cursor+ws2) -> fc_contribD -> fc_gatherD
// Same factorization as verified round-8 Path D:
//   out[j][o] = pos_j . (sum ft_n[o]) + sum h_n[o]
// Changes vs round 8 (both targeted at measured limiters):
//   * Wl packed as 4xfp16 (32 KB instead of 64 KB) -> LDS 48 KB -> 3 blk/CU
//     (occupancy 30% -> ~75% cap). fp16 weight rounding (5e-4 rel) is an
//     order below the existing fp16 ftfb storage rounding.
//   * gather batches 8 row-loads in flight (typical indegree = 8).
// ===========================================================================

__device__ __forceinline__ unsigned pack_h2(float a, float b) {
    return (unsigned)__half_as_ushort(__float2half(a))
         | ((unsigned)__half_as_ushort(__float2half(b)) << 16);
}

__device__ __forceinline__ float edge_dot(uint2 v, float qx, float qy, float qz) {
    const float f0 = __half2float(__ushort_as_half((unsigned short)(v.x)));
    const float f1 = __half2float(__ushort_as_half((unsigned short)(v.x >> 16)));
    const float f2 = __half2float(__ushort_as_half((unsigned short)(v.y)));
    const float f3 = __half2float(__ushort_as_half((unsigned short)(v.y >> 16)));
    return fmaf(qx, f0, fmaf(qy, f1, fmaf(qz, f2, f3)));
}

// --- contrib: GEMM -> dense ftfb16 row per point; bucket index per edge ----
__global__ __launch_bounds__(512, 4) void fc_contribD(
    const float* __restrict__ feat,     // [B, CIN, N]
    const float* __restrict__ theta,    // [3, CIN, COUT]
    const float* __restrict__ wbias,    // [CIN, COUT]
    const int*   __restrict__ nbh,      // [B, K, N]
    const float* __restrict__ pos,      // [B, 3, N]
    int*         __restrict__ cursor,   // [B, N]   (zeroed)
    int*         __restrict__ bucket,   // [B, N, CAP] source indices
    uint2*       __restrict__ ftfb,     // [B, N, 64] packed 4xfp16
    float*       __restrict__ ws2)      // [B, N, 64] fp32 overflow (zeroed)
{
    __shared__ uint2 Wl[CIN_ * COUT_];    // 32 KiB: 4xfp16 (t0,t1 | t2,wb)
    __shared__ float Fl[CIN_ * 64];       // 16 KiB -> total 48 KiB, 3 blk/CU

    const int tid  = threadIdx.x;
    const int lane = tid & 63;            // o
    const int w    = tid >> 6;            // wave 0..7

    const int blocks_per_b = N_ / 128;    // 128
    const int b     = blockIdx.x / blocks_per_b;
    const int nbase = (blockIdx.x % blocks_per_b) * 128;

    for (int e = tid; e < CIN_ * COUT_; e += 512) {
        const int i = e >> 6, o = e & 63;
        const float wx = theta[0 * CIN_ * COUT_ + i * COUT_ + o];
        const float wy = theta[1 * CIN_ * COUT_ + i * COUT_ + o];
        const float wz = theta[2 * CIN_ * COUT_ + i * COUT_ + o];
        const float wb = wbias[i * COUT_ + o];
        uint2 u;
        u.x = pack_h2(wx, wy);
        u.y = pack_h2(wz, wb);
        Wl[e] = u;
    }

    const float* featb = feat + (size_t)b * CIN_ * N_;
    const float* posb  = pos  + (size_t)b * 3 * N_;
    const int*   nbhb  = nbh  + (size_t)b * K_ * N_;
    int*         curb  = cursor + b * N_;
    int*         bkb   = bucket + (size_t)b * N_ * CAP_;
    uint2*       fbb   = ftfb + ((size_t)b * N_ << 6);
    float*       ws2b  = ws2 + ((size_t)b * N_ << 6);

    for (int t = 0; t < 2; ++t) {
        const int n0 = nbase + t * 64;
        const int nn = w * 8;             // this wave's 8 points

        __syncthreads();   // Wl ready (t=0) / previous Fl readers done
        for (int r = 0; r < 8; ++r) {
            const int i = r * 8 + w;
            Fl[i * 64 + lane] = featb[(size_t)i * N_ + n0 + lane];
        }

        // --- edge prep: lane l claims slot for (point l>>3, edge l&7) ------
        const int pe = lane >> 3;                 // local point 0..7
        const int ke = lane & 7;                  // edge 0..7
        const int ne = n0 + nn + pe;
        const int je = nbhb[ke * N_ + ne];
        const int sle = atomicAdd(&curb[je], 1);
        if (sle < CAP_) bkb[je * CAP_ + sle] = ne;   // 4-B scattered store

        __syncthreads();   // Fl ready

        float4 acc[8];
        #pragma unroll
        for (int j = 0; j < 8; ++j) acc[j] = make_float4(0.f, 0.f, 0.f, 0.f);

        #pragma unroll 2
        for (int i = 0; i < CIN_; ++i) {
            const uint2 wp = Wl[i * 64 + lane];   // ds_read_b64, 2-way = free
            const float2 w01 = __half22float2(*reinterpret_cast<const __half2*>(&wp.x));
            const float2 w23 = __half22float2(*reinterpret_cast<const __half2*>(&wp.y));
            const float4 fA = *(const float4*)&Fl[i * 64 + nn];     // broadcast
            const float4 fB = *(const float4*)&Fl[i * 64 + nn + 4]; // broadcast
            const float fs[8] = {fA.x, fA.y, fA.z, fA.w, fB.x, fB.y, fB.z, fB.w};
            #pragma unroll
            for (int j = 0; j < 8; ++j) {
                acc[j].x = fmaf(w01.x, fs[j], acc[j].x);
                acc[j].y = fmaf(w01.y, fs[j], acc[j].y);
                acc[j].z = fmaf(w23.x, fs[j], acc[j].z);
                acc[j].w = fmaf(w23.y, fs[j], acc[j].w);
            }
        }

        const unsigned long long ovf = __ballot(sle >= CAP_);   // bit = p*8+k

        #pragma unroll
        for (int p = 0; p < 8; ++p) {
            const int n = n0 + nn + p;
            const float px = posb[0 * N_ + n];
            const float py = posb[1 * N_ + n];
            const float pz = posb[2 * N_ + n];
            float4 a = acc[p];
            a.w = fmaf(-px, a.x, fmaf(-py, a.y, fmaf(-pz, a.z, a.w)));  // h

            // dense coalesced 8-B store: the ONLY per-point heavy write
            uint2 v;
            v.x = pack_h2(a.x, a.y);
            v.y = pack_h2(a.z, a.w);
            fbb[((size_t)n << 6) + lane] = v;

            // rare overflow edges: fp32 atomic into ws2 (wave-uniform masks)
            const unsigned m8 = (unsigned)((ovf >> (p * 8)) & 0xFFull);
            if (m8) {
                #pragma unroll
                for (int k = 0; k < 8; ++k) {
                    if ((m8 >> k) & 1) {
                        const int src = p * 8 + k;
                        const int jt = __shfl(je, src);
                        const float qx = posb[jt];              // broadcast
                        const float qy = posb[N_ + jt];
                        const float qz = posb[2 * N_ + jt];
                        const float c = fmaf(qx, a.x,
                                        fmaf(qy, a.y,
                                        fmaf(qz, a.z, a.w)));
                        atomicAdd(&ws2b[((size_t)jt << 6) + lane], c);
                    }
                }
            }
        }
    }
}

// --- gather: per target j, sum ftfb rows of its bucket sources -------------
__global__ __launch_bounds__(512, 4) void fc_gatherD(
    const uint2* __restrict__ ftfb,     // [B, N, 64]
    const int*   __restrict__ bucket,   // [B, N, CAP]
    const int*   __restrict__ cursor,   // [B, N] total in-degree
    const float* __restrict__ ws2,      // [B, N, 64] overflow sums
    const float* __restrict__ pos,      // [B, 3, N]
    const float* __restrict__ bias,
    float*       __restrict__ out)      // [B, COUT, N]
{
    __shared__ float T[64][65];          // 16.25 KiB
    const int tid  = threadIdx.x;
    const int lane = tid & 63;           // o
    const int w    = tid >> 6;           // 0..7

    const int tiles_per_b = N_ / 64;     // 256
    const int b  = blockIdx.x / tiles_per_b;
    const int n0 = (blockIdx.x % tiles_per_b) * 64;

    const uint2* fbb  = ftfb + ((size_t)b * N_ << 6);
    const int*   bkb  = bucket + (size_t)b * N_ * CAP_;
    const float* posb = pos + (size_t)b * 3 * N_;
    const float* ws2b = ws2 + ((size_t)b * N_ << 6);

    for (int g = 0; g < 8; ++g) {
        const int jj = w * 8 + g;
        const int j  = n0 + jj;
        const int cnt_tot = cursor[b * N_ + j];
        const int cnt = cnt_tot < CAP_ ? cnt_tot : CAP_;
        const float qx = posb[j];
        const float qy = posb[N_ + j];
        const float qz = posb[2 * N_ + j];

        // parallel index fetch: lane e holds bucket entry e
        const int myidx = (lane < cnt) ? bkb[j * CAP_ + lane] : 0;

        float acc = (cnt_tot > CAP_) ? ws2b[((size_t)j << 6) + lane] : 0.f;

        int e = 0;
        for (; e + 8 <= cnt; e += 8) {          // 8 row loads in flight
            int m[8];
            #pragma unroll
            for (int q = 0; q < 8; ++q) m[q] = __shfl(myidx, e + q);
            uint2 v[8];
            #pragma unroll
            for (int q = 0; q < 8; ++q) v[q] = fbb[((size_t)m[q] << 6) + lane];
            #pragma unroll
            for (int q = 0; q < 8; ++q) acc += edge_dot(v[q], qx, qy, qz);
        }
        for (; e + 4 <= cnt; e += 4) {          // 4 in flight
            const int m0 = __shfl(myidx, e + 0);
            const int m1 = __shfl(myidx, e + 1);
            const int m2 = __shfl(myidx, e + 2);
            const int m3 = __shfl(myidx, e + 3);
            const uint2 v0 = fbb[((size_t)m0 << 6) + lane];
            const uint2 v1 = fbb[((size_t)m1 << 6) + lane];
            const uint2 v2 = fbb[((size_t)m2 << 6) + lane];
            const uint2 v3 = fbb[((size_t)m3 << 6) + lane];
            acc += edge_dot(v0, qx, qy, qz);
            acc += edge_dot(v1, qx, qy, qz);
            acc += edge_dot(v2, qx, qy, qz);
            acc += edge_dot(v3, qx, qy, qz);
        }
        for (; e < cnt; ++e) {
            const int m = __shfl(myidx, e);
            const uint2 v = fbb[((size_t)m << 6) + lane];
            acc += edge_dot(v, qx, qy, qz);
        }
        T[jj][lane] = acc;
    }
    __syncthreads();

    float* outb = out + (size_t)b * COUT_ * N_;
    for (int r = 0; r < 8; ++r) {
        const int o = r * 8 + w;
        outb[(size_t)o * N_ + n0 + lane] = T[lane][o] + bias[o];  // coalesced
    }
}

// ===========================================================================
// PATH C (16 MiB ws): verified atomic-scatter fallback.
// ===========================================================================
__global__ __launch_bounds__(256) void flexconv_main(
    const float* __restrict__ feat,
    const float* __restrict__ theta,
    const float* __restrict__ wbias,
    const int*   __restrict__ nbh,
    const float* __restrict__ pos,
    float*       __restrict__ ws)
{
    __shared__ float4 Wl[CIN_ * COUT_];
    __shared__ float  Fl[CIN_ * 64];

    const int tid  = threadIdx.x;
    const int lane = tid & 63;
    const int w    = tid >> 6;

    const int blocks_per_b = N_ / 128;
    const int b     = blockIdx.x / blocks_per_b;
    const int nbase = (blockIdx.x % blocks_per_b) * 128;

    for (int e = tid; e < CIN_ * COUT_; e += 256) {
        const int i = e >> 6, o = e & 63;
        float4 wv;
        wv.x = theta[0 * CIN_ * COUT_ + i * COUT_ + o];
        wv.y = theta[1 * CIN_ * COUT_ + i * COUT_ + o];
        wv.z = theta[2 * CIN_ * COUT_ + i * COUT_ + o];
        wv.w = wbias[i * COUT_ + o];
        Wl[e] = wv;
    }

    const float* featb = feat + (size_t)b * CIN_ * N_;
    const float* posb  = pos  + (size_t)b * 3 * N_;
    const int*   nbhb  = nbh  + (size_t)b * K_ * N_;
    float*       wsb   = ws   + (size_t)b * N_ * COUT_;

    for (int t = 0; t < 2; ++t) {
        const int n0 = nbase + t * 64;

        __syncthreads();
        for (int r = 0; r < 16; ++r) {
            const int i = r * 4 + w;
            Fl[i * 64 + lane] = featb[(size_t)i * N_ + n0 + lane];
        }
        __syncthreads();

        for (int g = 0; g < 4; ++g) {
            const int nn = w * 16 + g * 4;
            float4 acc[4];
            #pragma unroll
            for (int j = 0; j < 4; ++j) acc[j] = make_float4(0.f, 0.f, 0.f, 0.f);

            #pragma unroll 8
            for (int i = 0; i < CIN_; ++i) {
                const float4 wv = Wl[i * 64 + lane];
                const float f0 = Fl[i * 64 + nn + 0];
                const float f1 = Fl[i * 64 + nn + 1];
                const float f2 = Fl[i * 64 + nn + 2];
                const float f3 = Fl[i * 64 + nn + 3];
                acc[0].x = fmaf(wv.x, f0, acc[0].x);
                acc[0].y = fmaf(wv.y, f0, acc[0].y);
                acc[0].z = fmaf(wv.z, f0, acc[0].z);
                acc[0].w = fmaf(wv.w, f0, acc[0].w);
                acc[1].x = fmaf(wv.x, f1, acc[1].x);
                acc[1].y = fmaf(wv.y, f1, acc[1].y);
                acc[1].z = fmaf(wv.z, f1, acc[1].z);
                acc[1].w = fmaf(wv.w, f1, acc[1].w);
                acc[2].x = fmaf(wv.x, f2, acc[2].x);
                acc[2].y = fmaf(wv.y, f2, acc[2].y);
                acc[2].z = fmaf(wv.z, f2, acc[2].z);
                acc[2].w = fmaf(wv.w, f2, acc[2].w);
                acc[3].x = fmaf(wv.x, f3, acc[3].x);
                acc[3].y = fmaf(wv.y, f3, acc[3].y);
                acc[3].z = fmaf(wv.z, f3, acc[3].z);
                acc[3].w = fmaf(wv.w, f3, acc[3].w);
            }

            #pragma unroll
            for (int j = 0; j < 4; ++j) {
                const int n = n0 + nn + j;
                const float px = posb[0 * N_ + n];
                const float py = posb[1 * N_ + n];
                const float pz = posb[2 * N_ + n];
                const float4 a = acc[j];
                #pragma unroll
                for (int k = 0; k < K_; ++k) {
                    const int idx = nbhb[k * N_ + n];
                    const float dx = posb[0 * N_ + idx] - px;
                    const float dy = posb[1 * N_ + idx] - py;
                    const float dz = posb[2 * N_ + idx] - pz;
                    const float c  = fmaf(dx, a.x, fmaf(dy, a.y, fmaf(dz, a.z, a.w)));
                    atomicAdd(&wsb[(size_t)idx * COUT_ + lane], c);
                }
            }
        }
    }
}

__global__ __launch_bounds__(256) void flexconv_finish(
    const float* __restrict__ ws,
    const float* __restrict__ bias,
    float*       __restrict__ out)
{
    __shared__ float T[64][65];
    const int tid  = threadIdx.x;
    const int lane = tid & 63;
    const int w    = tid >> 6;

    const int tiles_per_b = N_ / 64;
    const int b  = blockIdx.x / tiles_per_b;
    const int n0 = (blockIdx.x % tiles_per_b) * 64;

    const float* wsb = ws + (size_t)b * N_ * COUT_;
    for (int r = 0; r < 16; ++r) {
        const int nn = r * 4 + w;
        T[nn][lane] = wsb[(size_t)(n0 + nn) * COUT_ + lane];
    }
    __syncthreads();

    float* outb = out + (size_t)b * COUT_ * N_;
    for (int r = 0; r < 16; ++r) {
        const int o = r * 4 + w;
        outb[(size_t)o * N_ + n0 + lane] = T[lane][o] + bias[o];
    }
}

// ===========================================================================
extern "C" void kernel_launch(void* const* d_in, const int* in_sizes, int n_in,
                              void* d_out, int out_size, void* d_ws, size_t ws_size,
                              hipStream_t stream) {
    const float* features = (const float*)d_in[0];
    const float* theta    = (const float*)d_in[1];
    const float* wbias    = (const float*)d_in[2];
    const int*   nbh      = (const int*)  d_in[3];
    const float* pos      = (const float*)d_in[4];
    const float* bias     = (const float*)d_in[5];
    float* out = (float*)d_out;

    // ---- Path D2: index buckets + ftfb16 (~52.3 MiB, 3 nodes) ----
    {
        const size_t ftfb_bytes   = ((size_t)B_ * N_ << 6) * sizeof(uint2);  // 32 MiB
        const size_t bucket_bytes = (size_t)B_ * N_ * CAP_ * sizeof(int);    // 4 MiB
        const size_t cursor_bytes = (size_t)B_ * N_ * sizeof(int);           // 256 KiB
        const size_t ws2_bytes    = ((size_t)B_ * N_ << 6) * sizeof(float);  // 16 MiB

        size_t off = 0;
        uint2* ftfb   = (uint2*)((char*)d_ws + off); off += ftfb_bytes;
        int*   bucket = (int*)  ((char*)d_ws + off); off += bucket_bytes;
        int*   cursor = (int*)  ((char*)d_ws + off); off += cursor_bytes;
        float* ws2    = (float*)((char*)d_ws + off); off += ws2_bytes;

        if (ws_size >= off) {
            // one memset covers cursor + ws2 (contiguous)
            hipMemsetAsync(cursor, 0, cursor_bytes + ws2_bytes, stream);
            fc_contribD<<<B_ * (N_ / 128), 512, 0, stream>>>(features, theta, wbias,
                                                             nbh, pos, cursor,
                                                             bucket, ftfb, ws2);
            fc_gatherD<<<B_ * (N_ / 64), 512, 0, stream>>>(ftfb, bucket, cursor,
                                                           ws2, pos, bias, out);
            return;
        }
    }

    // ---- Path C: atomic fallback (16 MiB) ----
    {
        float* ws = (float*)d_ws;
        const size_t ws_bytes = (size_t)B_ * N_ * COUT_ * sizeof(float);
        hipMemsetAsync(ws, 0, ws_bytes, stream);
        flexconv_main<<<B_ * (N_ / 128), 256, 0, stream>>>(features, theta, wbias,
                                                           nbh, pos, ws);
        flexconv_finish<<<B_ * (N_ / 64), 256, 0, stream>>>(ws, bias, out);
    }
}